// Round 12
// baseline (319.431 us; speedup 1.0000x reference)
//
#include <hip/hip_runtime.h>
#include <math.h>

#define BB 8
#define LL 2048
#define DD 256

typedef float  f4_t __attribute__((ext_vector_type(4)));
typedef short  s8_t __attribute__((ext_vector_type(8)));

union S8U { s8_t v; unsigned u[4]; };

__device__ __forceinline__ unsigned bitsf(float x){ union{float f; unsigned u;} c; c.f=x; return c.u; }
__device__ __forceinline__ float fbits(unsigned u){ union{float f; unsigned u;} c; c.u=u; return c.f; }
// pack two fp32 -> two bf16 (truncate), elem0 in low half
__device__ __forceinline__ unsigned pkhi(float a, float b){ return (bitsf(a)>>16) | (bitsf(b)&0xffff0000u); }
// pack two fp32 -> two bf16 (round-nearest-ish)
__device__ __forceinline__ unsigned pkrn(float a, float b){
    unsigned ua = bitsf(a) + 0x8000u, ub = bitsf(b) + 0x8000u;
    return (ua>>16) | (ub&0xffff0000u);
}

// sigma: row e (0..31) of the key tile -> Vperm slot; makes P's MFMA C/D layout
// directly usable as the PV A-operand (slot k=8q+4a+b holds j=16a+4q+b).
__device__ __forceinline__ int vslot(int e){ return ((e>>2)&3)*8 + ((e>>4)<<2) + (e&3); }

// ---------------- MFMA flash attention (EXACT R3/R7 version — known-good) ----------------
// grid = 8 batches x 16 qblocks x (2048/klen) chunks; blk&7=batch (XCD affinity).
__global__ __launch_bounds__(256,1)
void attn_kernel(const float* __restrict__ c1, const float* __restrict__ c2,
                 const unsigned char* __restrict__ cmask,
                 float* __restrict__ o_out, float* __restrict__ mlp,
                 int klen, int split)
{
    __shared__ short Khi[32*264];
    __shared__ short Klo[32*264];
    __shared__ short Vp [256*34];

    const int tid  = threadIdx.x;
    const int lane = tid & 63;
    const int w    = tid >> 6;
    const int il   = lane & 15;
    const int quad = lane >> 4;

    const int blk  = blockIdx.x;
    const int bb   = blk & 7;
    const int qb   = (blk >> 3) & 15;
    const int half = split ? (blk >> 7) : 0;
    const int kb   = half * klen;

    const float* c1b = c1 + (size_t)bb * LL * DD;
    const float* c2b = c2 + (size_t)bb * LL * DD;
    const unsigned char* mb = cmask + (size_t)bb * LL;

    const int q0w = qb*128 + w*32;

    s8_t qh[2][8], ql[2][8];
#pragma unroll
    for (int nt = 0; nt < 2; ++nt) {
        const float* qp = c2b + (size_t)(q0w + 16*nt + il)*DD + quad*8;
#pragma unroll
        for (int kd = 0; kd < 8; ++kd) {
            float4 x0 = *(const float4*)(qp + kd*32);
            float4 x1 = *(const float4*)(qp + kd*32 + 4);
            float e[8] = {x0.x,x0.y,x0.z,x0.w,x1.x,x1.y,x1.z,x1.w};
            S8U h, l;
#pragma unroll
            for (int p2 = 0; p2 < 4; ++p2) {
                float a = e[2*p2], b = e[2*p2+1];
                h.u[p2] = pkhi(a, b);
                float alo = a - fbits(bitsf(a)&0xffff0000u);
                float blo = b - fbits(bitsf(b)&0xffff0000u);
                l.u[p2] = pkhi(alo, blo);
            }
            qh[nt][kd] = h.v; ql[nt][kd] = l.v;
        }
    }

    f4_t o[2][16];
#pragma unroll
    for (int mt = 0; mt < 2; ++mt)
#pragma unroll
        for (int n = 0; n < 16; ++n) o[mt][n] = (f4_t)0.0f;
    float m_s[2] = {-INFINITY, -INFINITY};
    float l_s[2] = {0.f, 0.f};

    const int NT = klen >> 5;
    float g[32];

#pragma unroll
    for (int e = 0; e < 32; ++e) g[e] = c1b[(size_t)(kb + e)*DD + tid];
#pragma unroll
    for (int e = 0; e < 32; ++e) {
        unsigned ub = bitsf(g[e]);
        Khi[e*264 + tid] = (short)(ub >> 16);
        float lo = g[e] - fbits(ub & 0xffff0000u);
        Klo[e*264 + tid] = (short)(bitsf(lo) >> 16);
    }
#pragma unroll
    for (int e = 0; e < 32; e += 2)
        ((unsigned*)Vp)[tid*17 + (vslot(e)>>1)] = pkrn(g[e], g[e+1]);
    __syncthreads();

    for (int kt = 0; kt < NT; ++kt) {
        const int k0 = kt << 5;
        if (kt + 1 < NT) {
#pragma unroll
            for (int e = 0; e < 32; ++e) g[e] = c1b[(size_t)(kb + k0 + 32 + e)*DD + tid];
        }

        f4_t acc[2][2];
#pragma unroll
        for (int mj = 0; mj < 2; ++mj)
#pragma unroll
            for (int nt = 0; nt < 2; ++nt) acc[mj][nt] = (f4_t)0.0f;

#pragma unroll
        for (int kd = 0; kd < 8; ++kd) {
            s8_t ah0 = *(const s8_t*)&Khi[(il     )*264 + kd*32 + quad*8];
            s8_t ah1 = *(const s8_t*)&Khi[(16 + il)*264 + kd*32 + quad*8];
            s8_t al0 = *(const s8_t*)&Klo[(il     )*264 + kd*32 + quad*8];
            s8_t al1 = *(const s8_t*)&Klo[(16 + il)*264 + kd*32 + quad*8];
#pragma unroll
            for (int nt = 0; nt < 2; ++nt) {
                acc[0][nt] = __builtin_amdgcn_mfma_f32_16x16x32_bf16(ah0, qh[nt][kd], acc[0][nt], 0,0,0);
                acc[1][nt] = __builtin_amdgcn_mfma_f32_16x16x32_bf16(ah1, qh[nt][kd], acc[1][nt], 0,0,0);
                acc[0][nt] = __builtin_amdgcn_mfma_f32_16x16x32_bf16(al0, qh[nt][kd], acc[0][nt], 0,0,0);
                acc[1][nt] = __builtin_amdgcn_mfma_f32_16x16x32_bf16(al1, qh[nt][kd], acc[1][nt], 0,0,0);
                acc[0][nt] = __builtin_amdgcn_mfma_f32_16x16x32_bf16(ah0, ql[nt][kd], acc[0][nt], 0,0,0);
                acc[1][nt] = __builtin_amdgcn_mfma_f32_16x16x32_bf16(ah1, ql[nt][kd], acc[1][nt], 0,0,0);
            }
        }

        unsigned mu[2];
#pragma unroll
        for (int mj = 0; mj < 2; ++mj)
            mu[mj] = *(const unsigned*)(mb + kb + k0 + 16*mj + 4*quad);

        f4_t p[2][2];
        float alpha_v[2];
#pragma unroll
        for (int nt = 0; nt < 2; ++nt) {
            const int ig = q0w + 16*nt + il;
            float mn = m_s[nt];
#pragma unroll
            for (int mj = 0; mj < 2; ++mj) {
#pragma unroll
                for (int b = 0; b < 4; ++b) {
                    int jg = kb + k0 + 16*mj + 4*quad + b;
                    float s = acc[mj][nt][b];
                    bool dead = (((mu[mj] >> (8*b)) & 0xff) != 0) || (jg == ig);
                    s = dead ? -INFINITY : s;
                    p[mj][nt][b] = s;
                    mn = fmaxf(mn, s);
                }
            }
            mn = fmaxf(mn, __shfl_xor(mn, 16, 64));
            mn = fmaxf(mn, __shfl_xor(mn, 32, 64));
            float al = __expf(m_s[nt] - mn);
            float rs = 0.f;
#pragma unroll
            for (int mj = 0; mj < 2; ++mj) {
#pragma unroll
                for (int b = 0; b < 4; ++b) {
                    float pe = __expf(p[mj][nt][b] - mn);
                    p[mj][nt][b] = pe;
                    rs += pe;
                }
            }
            rs += __shfl_xor(rs, 16, 64);
            rs += __shfl_xor(rs, 32, 64);
            l_s[nt] = l_s[nt]*al + rs;
            m_s[nt] = mn;
            alpha_v[nt] = al;
        }

#pragma unroll
        for (int mt = 0; mt < 2; ++mt) {
            float am[4];
#pragma unroll
            for (int b = 0; b < 4; ++b) am[b] = __shfl(alpha_v[mt], 4*quad + b, 64);
#pragma unroll
            for (int n = 0; n < 16; ++n) {
#pragma unroll
                for (int b = 0; b < 4; ++b) o[mt][n][b] *= am[b];
            }
        }

        s8_t ap[2];
#pragma unroll
        for (int mt = 0; mt < 2; ++mt) {
            S8U a;
            a.u[0] = pkrn(p[0][mt][0], p[0][mt][1]);
            a.u[1] = pkrn(p[0][mt][2], p[0][mt][3]);
            a.u[2] = pkrn(p[1][mt][0], p[1][mt][1]);
            a.u[3] = pkrn(p[1][mt][2], p[1][mt][3]);
            ap[mt] = a.v;
        }
#pragma unroll
        for (int n = 0; n < 16; ++n) {
            S8U bv;
#pragma unroll
            for (int dd = 0; dd < 4; ++dd)
                bv.u[dd] = ((const unsigned*)Vp)[(16*n + il)*17 + quad*4 + dd];
            o[0][n] = __builtin_amdgcn_mfma_f32_16x16x32_bf16(ap[0], bv.v, o[0][n], 0,0,0);
            o[1][n] = __builtin_amdgcn_mfma_f32_16x16x32_bf16(ap[1], bv.v, o[1][n], 0,0,0);
        }

        __syncthreads();
        if (kt + 1 < NT) {
#pragma unroll
            for (int e = 0; e < 32; ++e) {
                unsigned ub = bitsf(g[e]);
                Khi[e*264 + tid] = (short)(ub >> 16);
                float lo = g[e] - fbits(ub & 0xffff0000u);
                Klo[e*264 + tid] = (short)(bitsf(lo) >> 16);
            }
#pragma unroll
            for (int e = 0; e < 32; e += 2)
                ((unsigned*)Vp)[tid*17 + (vslot(e)>>1)] = pkrn(g[e], g[e+1]);
        }
        __syncthreads();
    }

    const int rbq = bb*LL + q0w;
    if (split) {
#pragma unroll
        for (int mt = 0; mt < 2; ++mt) {
            const int rbase = rbq + 16*mt + 4*quad;
#pragma unroll
            for (int n = 0; n < 16; ++n) {
                const int d = 16*n + il;
#pragma unroll
                for (int b = 0; b < 4; ++b)
                    o_out[(size_t)half*4194304 + (size_t)(rbase + b)*DD + d] = o[mt][n][b];
            }
        }
        if (lane < 16) {
#pragma unroll
            for (int nt = 0; nt < 2; ++nt) {
                int r = rbq + 16*nt + lane;
                *(float2*)(&mlp[((size_t)half*16384 + r)*2]) = make_float2(m_s[nt], l_s[nt]);
            }
        }
    } else {
#pragma unroll
        for (int mt = 0; mt < 2; ++mt) {
            float invl[4];
#pragma unroll
            for (int b = 0; b < 4; ++b) invl[b] = 1.0f / __shfl(l_s[mt], 4*quad + b, 64);
            const int rbase = rbq + 16*mt + 4*quad;
#pragma unroll
            for (int n = 0; n < 16; ++n) {
                const int d = 16*n + il;
#pragma unroll
                for (int b = 0; b < 4; ++b)
                    o_out[(size_t)(rbase + b)*DD + d] = o[mt][n][b] * invl[b];
            }
        }
    }
}

// ---------------- split-K flash combine, generalized to S partials ----------------
// Same math/structure as the R3/R7-proven 2-way combine, looped over S.
__global__ __launch_bounds__(256)
void combine_kernel(const float* __restrict__ Op, const float* __restrict__ mlp,
                    float* __restrict__ aug, int S)
{
    int t = blockIdx.x*256 + threadIdx.x;
    int r = t >> 6, c = (t & 63) << 2;
    float m[4], l[4];
    float M = -INFINITY;
    for (int s = 0; s < S; ++s) {
        m[s] = mlp[((size_t)s*16384 + r)*2];
        l[s] = mlp[((size_t)s*16384 + r)*2 + 1];
        M = fmaxf(M, m[s]);
    }
    float a[4], Lt = 0.f;
    for (int s = 0; s < S; ++s) { a[s] = __expf(m[s] - M); Lt += a[s]*l[s]; }
    float inv = 1.0f / Lt;
    f4_t acc = (f4_t)0.0f;
    for (int s = 0; s < S; ++s) {
        f4_t x = *(const f4_t*)(Op + (size_t)s*4194304 + (size_t)r*DD + c);
        acc += x * a[s];
    }
    *(f4_t*)(aug + (size_t)r*DD + c) = acc * inv;
}

// ---------------- prep (EXACT R3/R7 version) ----------------
__global__ __launch_bounds__(256)
void prep_kernel(const float* __restrict__ Wf, const float* __restrict__ Wg,
                 unsigned* __restrict__ Whi, unsigned* __restrict__ Wlo,
                 float* __restrict__ gw)
{
    if (blockIdx.x == 384) {
#pragma unroll
        for (int i = 0; i < 3; ++i) {
            int kl = threadIdx.x;
            float v = (i == 0) ? (Wg[kl] + Wg[768 + kl])
                    : (i == 1) ? (Wg[256 + kl] - Wg[768 + kl])
                               :  Wg[512 + kl];
            gw[i*256 + kl] = v;
        }
        return;
    }
    int t    = blockIdx.x*256 + threadIdx.x;    // [0, 98304)
    int p    = t & 3;
    int lane = (t >> 2) & 63;
    int nt   = (t >> 8) & 15;
    int g2   = t >> 12;                          // kc*3 + seg, [0,24)
    int seg  = g2 % 3;
    int kc   = g2 / 3;
    int kl   = kc*32 + (lane >> 4)*8 + 2*p;
    int n    = nt*16 + (lane & 15);
    float v0, v1;
    if (seg == 0) {
        v0 = Wf[(size_t)kl*DD + n]       + Wf[(size_t)(768 + kl)*DD + n];
        v1 = Wf[(size_t)(kl + 1)*DD + n] + Wf[(size_t)(769 + kl)*DD + n];
    } else if (seg == 1) {
        v0 = Wf[(size_t)(256 + kl)*DD + n] - Wf[(size_t)(768 + kl)*DD + n];
        v1 = Wf[(size_t)(257 + kl)*DD + n] - Wf[(size_t)(769 + kl)*DD + n];
    } else {
        v0 = Wf[(size_t)(512 + kl)*DD + n];
        v1 = Wf[(size_t)(513 + kl)*DD + n];
    }
    Whi[t] = pkhi(v0, v1);
    float l0 = v0 - fbits(bitsf(v0) & 0xffff0000u);
    float l1 = v1 - fbits(bitsf(v1) & 0xffff0000u);
    Wlo[t] = pkrn(l0, l1);
}

// ---------------- MFMA fusion (EXACT R7 version — known-robust) ----------------
__global__ __launch_bounds__(256,1)
void fusion_mfma(const float* __restrict__ c2, const float* __restrict__ aug,
                 const unsigned* __restrict__ Whi, const unsigned* __restrict__ Wlo,
                 const float* __restrict__ gw, const float* __restrict__ bg,
                 const float* __restrict__ bf, float* __restrict__ out)
{
    __shared__ float gwL[768];
    __shared__ float gv[64];

    const int tid  = threadIdx.x;
    const int lane = tid & 63;
    const int w    = tid >> 6;
    const int il   = lane & 15;
    const int quad = lane >> 4;
    const size_t row0 = (size_t)blockIdx.x * 64;

    const float* c2b  = c2 + row0*DD;
    const float* augb = aug + row0*DD;

    for (int i = tid; i < 768; i += 256) gwL[i] = gw[i];
    __syncthreads();

    f4_t acc[4][4];
#pragma unroll
    for (int mt = 0; mt < 4; ++mt)
#pragma unroll
        for (int nt = 0; nt < 4; ++nt) acc[mt][nt] = (f4_t)0.0f;
    float gp[4] = {0.f, 0.f, 0.f, 0.f};

    for (int kc = 0; kc < 8; ++kc) {
        s8_t za[4], zb[4], zc[4];
        const int c0 = kc*32 + quad*8;
#pragma unroll
        for (int mt = 0; mt < 4; ++mt) {
            const float* pr = c2b  + (size_t)(16*mt + il)*DD + c0;
            const float* pu = augb + (size_t)(16*mt + il)*DD + c0;
            float4 a0 = *(const float4*)pr, a1 = *(const float4*)(pr + 4);
            float4 u0 = *(const float4*)pu, u1 = *(const float4*)(pu + 4);
            float ea[8] = {a0.x,a0.y,a0.z,a0.w,a1.x,a1.y,a1.z,a1.w};
            float eu[8] = {u0.x,u0.y,u0.z,u0.w,u1.x,u1.y,u1.z,u1.w};
#pragma unroll
            for (int j = 0; j < 8; ++j)
                gp[mt] += ea[j]*gwL[c0+j] + eu[j]*gwL[256+c0+j] + (ea[j]*eu[j])*gwL[512+c0+j];
            S8U A, U, Pd;
#pragma unroll
            for (int p = 0; p < 4; ++p) {
                A.u[p]  = pkrn(ea[2*p], ea[2*p+1]);
                U.u[p]  = pkrn(eu[2*p], eu[2*p+1]);
                Pd.u[p] = pkrn(ea[2*p]*eu[2*p], ea[2*p+1]*eu[2*p+1]);
            }
            za[mt] = A.v; zb[mt] = U.v; zc[mt] = Pd.v;
        }
#pragma unroll
        for (int nt = 0; nt < 4; ++nt) {
            const int ntg = w*4 + nt;
            const size_t f0 = ((size_t)((kc*3 + 0)*16 + ntg)*64 + lane)*4;
            const size_t f1 = ((size_t)((kc*3 + 1)*16 + ntg)*64 + lane)*4;
            const size_t f2 = ((size_t)((kc*3 + 2)*16 + ntg)*64 + lane)*4;
            s8_t w0h = *(const s8_t*)(Whi + f0), w0l = *(const s8_t*)(Wlo + f0);
            s8_t w1h = *(const s8_t*)(Whi + f1), w1l = *(const s8_t*)(Wlo + f1);
            s8_t w2h = *(const s8_t*)(Whi + f2), w2l = *(const s8_t*)(Wlo + f2);
#pragma unroll
            for (int mt = 0; mt < 4; ++mt) {
                acc[mt][nt] = __builtin_amdgcn_mfma_f32_16x16x32_bf16(za[mt], w0h, acc[mt][nt], 0,0,0);
                acc[mt][nt] = __builtin_amdgcn_mfma_f32_16x16x32_bf16(za[mt], w0l, acc[mt][nt], 0,0,0);
                acc[mt][nt] = __builtin_amdgcn_mfma_f32_16x16x32_bf16(zb[mt], w1h, acc[mt][nt], 0,0,0);
                acc[mt][nt] = __builtin_amdgcn_mfma_f32_16x16x32_bf16(zb[mt], w1l, acc[mt][nt], 0,0,0);
                acc[mt][nt] = __builtin_amdgcn_mfma_f32_16x16x32_bf16(zc[mt], w2h, acc[mt][nt], 0,0,0);
                acc[mt][nt] = __builtin_amdgcn_mfma_f32_16x16x32_bf16(zc[mt], w2l, acc[mt][nt], 0,0,0);
            }
        }
    }

    // gate reduce over the 4 quad lanes; wave 0 publishes
#pragma unroll
    for (int mt = 0; mt < 4; ++mt) {
        float gg = gp[mt];
        gg += __shfl_xor(gg, 16, 64);
        gg += __shfl_xor(gg, 32, 64);
        if (w == 0 && quad == 0) gv[16*mt + il] = gg;
    }
    __syncthreads();
    if (tid < 64) gv[tid] = 1.0f / (1.0f + __expf(-(gv[tid] + bg[0])));
    __syncthreads();

    // epilogue: row = 16mt + 4quad + b, col = 64w + 16nt + il
#pragma unroll
    for (int nt = 0; nt < 4; ++nt) {
        const int col = w*64 + nt*16 + il;
        const float bfv = bf[col];
#pragma unroll
        for (int mt = 0; mt < 4; ++mt) {
#pragma unroll
            for (int b = 0; b < 4; ++b) {
                const int r = 16*mt + 4*quad + b;
                const float g = gv[r];
                const float cc = c2b[(size_t)r*DD + col];
                out[(row0 + r)*DD + col] = g * tanhf(acc[mt][nt][b] + bfv) + (1.f - g) * cc;
            }
        }
    }
}

extern "C" void kernel_launch(void* const* d_in, const int* in_sizes, int n_in,
                              void* d_out, int out_size, void* d_ws, size_t ws_size,
                              hipStream_t stream)
{
    const float* c1 = (const float*)d_in[0];
    const float* c2 = (const float*)d_in[1];
    const unsigned char* cmask = (const unsigned char*)d_in[2];
    const float* Wf = (const float*)d_in[3];
    const float* bf = (const float*)d_in[4];
    const float* Wg = (const float*)d_in[5];
    const float* bg = (const float*)d_in[6];

    // ws layout: Op[S*16384*256] | mlp[S*16384*2] | aug[16384*256]
    // Wfrag (Whi/Wlo/gw) ALIASES Op: prep runs after combine, when Op is dead.
    const size_t op1        = (size_t)16384 * 256;
    const size_t aug_elems  = (size_t)16384 * 256;
    const size_t frag_elems = (size_t)98304;   // uints per buffer
    const size_t need4 = (4*op1 + (size_t)4*16384*2 + aug_elems) * sizeof(float);
    const size_t need2 = (2*op1 + (size_t)2*16384*2 + aug_elems) * sizeof(float);
    const size_t need_nosplit = (aug_elems + 2*frag_elems + 768) * sizeof(float);

    int S;
    if      (ws_size >= need4) S = 4;
    else if (ws_size >= need2) S = 2;
    else                       S = 1;

    float* wsf = (float*)d_ws;
    float *Op, *mlp, *aug;
    unsigned *Whi, *Wlo; float *gw;
    if (S > 1) {
        Op  = wsf;
        mlp = wsf + (size_t)S*op1;
        aug = mlp + (size_t)S*16384*2;
        Whi = (unsigned*)Op; Wlo = Whi + frag_elems; gw = (float*)(Wlo + frag_elems);
    } else {
        Op  = wsf; mlp = wsf; aug = wsf;
        Whi = (unsigned*)(wsf + aug_elems); Wlo = Whi + frag_elems; gw = (float*)(Wlo + frag_elems);
        (void)need_nosplit;
    }

    if (S == 4) {
        attn_kernel<<<dim3(512), dim3(256), 0, stream>>>(c1, c2, cmask, Op, mlp, 512, 1);
        combine_kernel<<<dim3(4096), dim3(256), 0, stream>>>(Op, mlp, aug, 4);
    } else if (S == 2) {
        attn_kernel<<<dim3(256), dim3(256), 0, stream>>>(c1, c2, cmask, Op, mlp, 1024, 1);
        combine_kernel<<<dim3(4096), dim3(256), 0, stream>>>(Op, mlp, aug, 2);
    } else {
        attn_kernel<<<dim3(128), dim3(256), 0, stream>>>(c1, c2, cmask, aug, mlp, 2048, 0);
    }
    prep_kernel<<<dim3(385), dim3(256), 0, stream>>>(Wf, Wg, Whi, Wlo, gw);
    fusion_mfma<<<dim3(256), dim3(256), 0, stream>>>(c2, aug, Whi, Wlo, gw, bg, bf, (float*)d_out);
}